// Round 2
// baseline (570.498 us; speedup 1.0000x reference)
//
#include <hip/hip_runtime.h>

typedef unsigned short ushort_t;
typedef __attribute__((ext_vector_type(8))) short short8;
typedef __attribute__((ext_vector_type(4))) float f32x4;

#define BB 512
#define TT 2048
#define DD 64

__device__ __forceinline__ ushort_t f2b(float f) {
    union { float f; unsigned int i; } v; v.f = f;
    unsigned int u = v.i;
    unsigned int r = (u + 0x7fffu + ((u >> 16) & 1u)) >> 16;
    return (ushort_t)r;
}

// ---------------- Kernel 1: u_repr = mean over T of latent (f32 in, f32 out) ----------------
__global__ __launch_bounds__(1024) void k_umean(const float* __restrict__ lat,
                                                float* __restrict__ u) {
    int b = blockIdx.x;
    int tid = threadIdx.x;
    int cg = tid & 15;       // col group (float4)
    int rs = tid >> 4;       // row slot in [0,64)
    const float* base = lat + (size_t)b * TT * DD;
    float acc[4] = {0.f, 0.f, 0.f, 0.f};
#pragma unroll 4
    for (int k = 0; k < 32; k++) {
        int r = rs + 64 * k;
        float4 vv = *reinterpret_cast<const float4*>(base + (size_t)r * DD + cg * 4);
        acc[0] += vv.x; acc[1] += vv.y; acc[2] += vv.z; acc[3] += vv.w;
    }
    __shared__ float sm[64][64];
#pragma unroll
    for (int j = 0; j < 4; j++) sm[rs][cg * 4 + j] = acc[j];
    __syncthreads();
    {
        int col = tid & 63, g = tid >> 6;   // g in [0,16)
        float p = 0.0f;
#pragma unroll
        for (int k = 0; k < 4; k++) p += sm[g + 16 * k][col];
        sm[g][col] = p;  // rows <16 are read only by their own writer thread
    }
    __syncthreads();
    if (tid < 64) {
        float tot = 0.0f;
#pragma unroll
        for (int g = 0; g < 16; g++) tot += sm[g][tid];
        u[(size_t)b * DD + tid] = tot * (1.0f / (float)TT);
    }
}

// ---------------- Kernel 2: E_j, Z, top-2 argmax of b_j ----------------
__global__ __launch_bounds__(512) void k_logits(const float* __restrict__ u,
                                                const float* __restrict__ Wu,
                                                const float* __restrict__ Ws,
                                                float* __restrict__ E,
                                                float* __restrict__ miscf,
                                                int* __restrict__ misci) {
    __shared__ float v[64];
    __shared__ float rv[512];
    __shared__ int ri[512];
    int tid = threadIdx.x;
    if (tid < 64) {
        float s = 0.0f;
        for (int h = 0; h < 32; h++) s += Wu[tid * 32 + h] * Ws[32 + h];
        v[tid] = s;
    }
    __syncthreads();
    float bj = 0.0f;
    for (int d = 0; d < 64; d++) bj += u[(size_t)tid * DD + d] * v[d];
    // max-with-index reduce (first index on ties, like jnp.argmax)
    rv[tid] = bj; ri[tid] = tid;
    __syncthreads();
    for (int off = 256; off > 0; off >>= 1) {
        if (tid < off) {
            float v2 = rv[tid + off]; int i2 = ri[tid + off];
            if (v2 > rv[tid] || (v2 == rv[tid] && i2 < ri[tid])) { rv[tid] = v2; ri[tid] = i2; }
        }
        __syncthreads();
    }
    float maxb = rv[0]; int j1 = ri[0];
    __syncthreads();
    float e = expf(bj - maxb);
    E[tid] = e;
    rv[tid] = e;
    __syncthreads();
    for (int off = 256; off > 0; off >>= 1) {
        if (tid < off) rv[tid] += rv[tid + off];
        __syncthreads();
    }
    float Z = rv[0];
    __syncthreads();
    rv[tid] = (tid == j1) ? -3.4e38f : bj; ri[tid] = tid;
    __syncthreads();
    for (int off = 256; off > 0; off >>= 1) {
        if (tid < off) {
            float v2 = rv[tid + off]; int i2 = ri[tid + off];
            if (v2 > rv[tid] || (v2 == rv[tid] && i2 < ri[tid])) { rv[tid] = v2; ri[tid] = i2; }
        }
        __syncthreads();
    }
    if (tid == 0) { miscf[0] = Z; misci[1] = j1; misci[2] = ri[0]; }
}

// ---------------- Kernel 3: per-row level partition -> cross -> cbias ----------------
__global__ __launch_bounds__(256) void k_levels(const float* __restrict__ u,
                                                const float* __restrict__ E,
                                                const float* __restrict__ miscf,
                                                const int* __restrict__ misci,
                                                const float* __restrict__ lw,
                                                const float* __restrict__ Wf,
                                                const float* __restrict__ bfv,
                                                float* __restrict__ cbias) {
    int i = blockIdx.x;
    int tid = threadIdx.x;
    __shared__ float w[512];
    __shared__ signed char lvl[512];
    __shared__ float r1[256], r2[256], r3[256];
    __shared__ float crossS[64];
    __shared__ float lr[4][3][64];

    float Z = miscf[0];
    float denom = Z - E[i];
    for (int j = tid; j < 512; j += 256) w[j] = (j == i) ? 0.0f : (E[j] / denom);
    __syncthreads();
    float p = 0.0f;
    for (int j = tid; j < 512; j += 256) p += w[j];
    r1[tid] = p;
    __syncthreads();
    for (int off = 128; off > 0; off >>= 1) {
        if (tid < off) r1[tid] += r1[tid + off];
        __syncthreads();
    }
    float mean0 = r1[0] / 511.0f;
    __syncthreads();
    float pa = 0.0f, ca = 0.0f, c1 = 0.0f;
    for (int j = tid; j < 512; j += 256) {
        if (j != i) {
            float wj = w[j];
            if (wj <= mean0) c1 += 1.0f;
            else { pa += wj; ca += 1.0f; }
        }
    }
    r1[tid] = pa; r2[tid] = ca; r3[tid] = c1;
    __syncthreads();
    for (int off = 128; off > 0; off >>= 1) {
        if (tid < off) { r1[tid] += r1[tid + off]; r2[tid] += r2[tid + off]; r3[tid] += r3[tid + off]; }
        __syncthreads();
    }
    float asum1 = r1[0], cact = r2[0], cnt1 = r3[0];
    float mean1 = asum1 / fmaxf(cact, 1.0f);
    __syncthreads();
    float c2 = 0.0f;
    for (int j = tid; j < 512; j += 256) {
        signed char l;
        if (j == i) l = -1;
        else {
            float wj = w[j];
            if (wj <= mean0) l = 0;
            else if (wj <= mean1) { l = 1; c2 += 1.0f; }
            else l = 2;
        }
        lvl[j] = l;
    }
    r1[tid] = c2;
    __syncthreads();
    for (int off = 128; off > 0; off >>= 1) {
        if (tid < off) r1[tid] += r1[tid + off];
        __syncthreads();
    }
    float cnt2 = r1[0];
    float cnt3 = cact - cnt2;
    __syncthreads();
    int d = tid & 63, g = tid >> 6;
    float a0 = 0.0f, a1 = 0.0f, a2 = 0.0f;
    for (int j = g; j < 512; j += 4) {
        signed char l = lvl[j];
        float uv = u[(size_t)j * DD + d];
        if (l == 0) a0 += uv;
        else if (l == 1) a1 += uv;
        else if (l == 2) a2 += uv;
    }
    lr[g][0][d] = a0; lr[g][1][d] = a1; lr[g][2][d] = a2;
    __syncthreads();
    if (tid < 64) {
        float s0 = 0.0f, s1 = 0.0f, s2 = 0.0f;
#pragma unroll
        for (int gg = 0; gg < 4; gg++) { s0 += lr[gg][0][tid]; s1 += lr[gg][1][tid]; s2 += lr[gg][2][tid]; }
        int j1 = misci[1], j2 = misci[2];
        int fb = (j1 == i) ? j2 : j1;
        float L1 = (cnt1 > 0.0f) ? s0 / cnt1 : 0.0f;
        float L2 = (cnt2 > 0.0f) ? s1 / cnt2 : 0.0f;
        float L3 = (cnt3 > 0.0f) ? s2 / cnt3 : u[(size_t)fb * DD + tid];
        crossS[tid] = lw[0] * L1 + lw[1] * L2 + lw[2] * L3;
    }
    __syncthreads();
    if (tid < 64) {
        int n = tid;
        float s = 0.0f;
        for (int dd = 0; dd < 64; dd++) s += crossS[dd] * Wf[(64 + dd) * 64 + n];
        cbias[(size_t)i * DD + n] = s + bfv[n];
    }
}

// ---------------- Kernel 4: out = LN(latent @ bf16(Wf_top + I) + cbias[b]) ----------------
__global__ __launch_bounds__(256) void k_fused(const float* __restrict__ lat,
                                               const float* __restrict__ Wf,
                                               const float* __restrict__ cbias,
                                               const float* __restrict__ gamma,
                                               const float* __restrict__ beta,
                                               float* __restrict__ out) {
    int tid = threadIdx.x;
    int lane = tid & 63, wv = tid >> 6;
    int lo = lane & 15, quad = lane >> 4;
    long wid = (long)blockIdx.x * 4 + wv;   // [0, 16384)

    // B fragments of W' = Wf_top + I  (B[k][n], k = 32*s + 8*quad + j, n = 16*c + lo)
    short8 bfr[4][2];
#pragma unroll
    for (int c = 0; c < 4; c++) {
        int n = 16 * c + lo;
#pragma unroll
        for (int s = 0; s < 2; s++) {
            short8 t;
#pragma unroll
            for (int j = 0; j < 8; j++) {
                int k = 32 * s + 8 * quad + j;
                float vv = Wf[k * 64 + n] + (k == n ? 1.0f : 0.0f);
                t[j] = (short)f2b(vv);
            }
            bfr[c][s] = t;
        }
    }
    float ga[4], be[4], cb[4];
    int b = (int)(wid >> 5);  // 32 wids (64 rows each) per batch element
#pragma unroll
    for (int c = 0; c < 4; c++) {
        int n = 16 * c + lo;
        ga[c] = gamma[n];
        be[c] = beta[n];
        cb[c] = cbias[(size_t)b * DD + n];
    }

    for (int t4 = 0; t4 < 4; t4++) {
        long row0 = (wid * 4 + t4) * 16;
        const float* ap = lat + (size_t)(row0 + lo) * DD + quad * 8;
        float4 f0 = *reinterpret_cast<const float4*>(ap);
        float4 f1 = *reinterpret_cast<const float4*>(ap + 4);
        float4 f2 = *reinterpret_cast<const float4*>(ap + 32);
        float4 f3 = *reinterpret_cast<const float4*>(ap + 36);
        short8 a0, a1;
        a0[0] = (short)f2b(f0.x); a0[1] = (short)f2b(f0.y);
        a0[2] = (short)f2b(f0.z); a0[3] = (short)f2b(f0.w);
        a0[4] = (short)f2b(f1.x); a0[5] = (short)f2b(f1.y);
        a0[6] = (short)f2b(f1.z); a0[7] = (short)f2b(f1.w);
        a1[0] = (short)f2b(f2.x); a1[1] = (short)f2b(f2.y);
        a1[2] = (short)f2b(f2.z); a1[3] = (short)f2b(f2.w);
        a1[4] = (short)f2b(f3.x); a1[5] = (short)f2b(f3.y);
        a1[6] = (short)f2b(f3.z); a1[7] = (short)f2b(f3.w);

        f32x4 acc[4];
#pragma unroll
        for (int c = 0; c < 4; c++) { acc[c] = (f32x4){0.f, 0.f, 0.f, 0.f}; }
#pragma unroll
        for (int c = 0; c < 4; c++) {
            acc[c] = __builtin_amdgcn_mfma_f32_16x16x32_bf16(a0, bfr[c][0], acc[c], 0, 0, 0);
            acc[c] = __builtin_amdgcn_mfma_f32_16x16x32_bf16(a1, bfr[c][1], acc[c], 0, 0, 0);
        }
        float y[4][4];
#pragma unroll
        for (int c = 0; c < 4; c++)
#pragma unroll
            for (int r = 0; r < 4; r++) y[c][r] = acc[c][r] + cb[c];
#pragma unroll
        for (int r = 0; r < 4; r++) {
            float s = y[0][r] + y[1][r] + y[2][r] + y[3][r];
            float q = y[0][r] * y[0][r] + y[1][r] * y[1][r] + y[2][r] * y[2][r] + y[3][r] * y[3][r];
#pragma unroll
            for (int m = 1; m < 16; m <<= 1) {
                s += __shfl_xor(s, m, 64);
                q += __shfl_xor(q, m, 64);
            }
            float mean = s * (1.0f / 64.0f);
            float var = q * (1.0f / 64.0f) - mean * mean;
            float rstd = rsqrtf(var + 1e-5f);
            long row = row0 + quad * 4 + r;
#pragma unroll
            for (int c = 0; c < 4; c++) {
                float o = ga[c] * (y[c][r] - mean) * rstd + be[c];
                out[(size_t)row * DD + 16 * c + lo] = o;
            }
        }
    }
}

extern "C" void kernel_launch(void* const* d_in, const int* in_sizes, int n_in,
                              void* d_out, int out_size, void* d_ws, size_t ws_size,
                              hipStream_t stream) {
    const float* lat   = (const float*)d_in[0];
    // d_in[1]=Wx, d_in[2]=bx, d_in[6]=bs: dead (cancel in softmax/argmax)
    const float* Wu    = (const float*)d_in[3];
    // d_in[4]=bu: dead (constant shift in b_j cancels)
    const float* Ws    = (const float*)d_in[5];
    const float* lw    = (const float*)d_in[7];
    const float* Wf    = (const float*)d_in[8];
    const float* bfv   = (const float*)d_in[9];
    const float* gamma = (const float*)d_in[10];
    const float* beta  = (const float*)d_in[11];
    float* out = (float*)d_out;

    char* ws = (char*)d_ws;
    float* u     = (float*)(ws);                 // 512*64*4 = 131072 B
    float* E     = (float*)(ws + 131072);        // 2048 B
    float* miscf = (float*)(ws + 133120);        // 256 B
    int*   misci = (int*)(ws + 133120);
    float* cbias = (float*)(ws + 133376);        // 131072 B

    k_umean<<<BB, 1024, 0, stream>>>(lat, u);
    k_logits<<<1, 512, 0, stream>>>(u, Wu, Ws, E, miscf, misci);
    k_levels<<<BB, 256, 0, stream>>>(u, E, miscf, misci, lw, Wf, bfv, cbias);
    k_fused<<<4096, 256, 0, stream>>>(lat, Wf, cbias, gamma, beta, out);
}